// Round 1
// baseline (854.963 us; speedup 1.0000x reference)
//
#include <hip/hip_runtime.h>

#define DIM 128
#define NCLS 10

// ---------------- CSR build ----------------
__global__ void k_hist(const int* __restrict__ ei, int E, int* __restrict__ deg) {
    int e = blockIdx.x * 256 + threadIdx.x;
    if (e < E) atomicAdd(&deg[ei[E + e]], 1);   // v = ei[1][e]
}

__global__ void k_scan(const int* __restrict__ deg, int* __restrict__ row_start,
                       int* __restrict__ cursor, int n, int E) {
    __shared__ int sums[256];
    int tid = threadIdx.x;
    int per = (n + 255) / 256;
    int s0 = tid * per, s1 = min(s0 + per, n);
    int s = 0;
    for (int i = s0; i < s1; i++) s += deg[i];
    sums[tid] = s;
    __syncthreads();
    if (tid == 0) {
        int acc = 0;
        for (int i = 0; i < 256; i++) { int t = sums[i]; sums[i] = acc; acc += t; }
    }
    __syncthreads();
    int acc = sums[tid];
    for (int i = s0; i < s1; i++) { row_start[i] = acc; cursor[i] = acc; acc += deg[i]; }
    if (tid == 0) row_start[n] = E;
}

__global__ void k_fill(const int* __restrict__ ei, int E, int* __restrict__ cursor,
                       int* __restrict__ csr) {
    int e = blockIdx.x * 256 + threadIdx.x;
    if (e < E) {
        int u = ei[e], v = ei[E + e];
        int pos = atomicAdd(&cursor[v], 1);
        csr[pos] = u;
    }
}

// ---------------- LayerNorm ----------------
__global__ void k_ln(const float* __restrict__ h, const float* __restrict__ gg,
                     const float* __restrict__ bb, float* __restrict__ hn, int n) {
    int wid = (blockIdx.x * 256 + threadIdx.x) >> 6;
    int lane = threadIdx.x & 63;
    if (wid >= n) return;
    float2 v = ((const float2*)(h + (size_t)wid * DIM))[lane];
    float s = v.x + v.y, q = v.x * v.x + v.y * v.y;
#pragma unroll
    for (int o = 32; o; o >>= 1) { s += __shfl_xor(s, o); q += __shfl_xor(q, o); }
    float m = s * (1.f / DIM);
    float var = q * (1.f / DIM) - m * m;
    float inv = rsqrtf(var + 1e-5f);
    float2 g2 = ((const float2*)gg)[lane], b2 = ((const float2*)bb)[lane];
    float2 o2;
    o2.x = (v.x - m) * inv * g2.x + b2.x;
    o2.y = (v.y - m) * inv * g2.y + b2.y;
    ((float2*)(hn + (size_t)wid * DIM))[lane] = o2;
}

// ---------------- agg gather + action nets (agg never materialized) ----------------
__global__ void k_action(const float* __restrict__ hn, const int* __restrict__ row_start,
                         const int* __restrict__ csr,
                         const float* __restrict__ Wair, const float* __restrict__ Wain,
                         const float* __restrict__ bain,
                         const float* __restrict__ Waor, const float* __restrict__ Waon,
                         const float* __restrict__ baon,
                         const float* __restrict__ gin_l, const float* __restrict__ gout_l,
                         int* __restrict__ in_bit, int* __restrict__ out_bit, int n) {
    int wid = (blockIdx.x * 256 + threadIdx.x) >> 6;
    int lane = threadIdx.x & 63;
    if (wid >= n) return;
    int d0 = lane * 2;
    int base = row_start[wid], end = row_start[wid + 1];
    double ax = 0.0, ay = 0.0;
    for (int off = base; off < end; off += 64) {
        int m = min(64, end - off);
        int myu = (lane < m) ? csr[off + lane] : 0;
        for (int i = 0; i < m; i++) {
            int u = __shfl(myu, i);
            float2 t = *(const float2*)(hn + (size_t)u * DIM + d0);
            ax += t.x; ay += t.y;
        }
    }
    float2 hx = *(const float2*)(hn + (size_t)wid * DIM + d0);
    float4 wir = *(const float4*)(Wair + d0 * 2);
    float4 win = *(const float4*)(Wain + d0 * 2);
    float4 wor = *(const float4*)(Waor + d0 * 2);
    float4 won = *(const float4*)(Waon + d0 * 2);
    float axf = (float)ax, ayf = (float)ay;
    float pi0 = hx.x * wir.x + hx.y * wir.z + axf * win.x + ayf * win.z;
    float pi1 = hx.x * wir.y + hx.y * wir.w + axf * win.y + ayf * win.w;
    float po0 = hx.x * wor.x + hx.y * wor.z + axf * won.x + ayf * won.z;
    float po1 = hx.x * wor.y + hx.y * wor.w + axf * won.y + ayf * won.w;
#pragma unroll
    for (int o = 32; o; o >>= 1) {
        pi0 += __shfl_xor(pi0, o); pi1 += __shfl_xor(pi1, o);
        po0 += __shfl_xor(po0, o); po1 += __shfl_xor(po1, o);
    }
    if (lane == 0) {
        float li0 = pi0 + bain[0] + gin_l[(size_t)wid * 2 + 0];
        float li1 = pi1 + bain[1] + gin_l[(size_t)wid * 2 + 1];
        float lo0 = po0 + baon[0] + gout_l[(size_t)wid * 2 + 0];
        float lo1 = po1 + baon[1] + gout_l[(size_t)wid * 2 + 1];
        in_bit[wid]  = (li0 >= li1) ? 1 : 0;  // argmax==0 on tie
        out_bit[wid] = (lo0 >= lo1) ? 1 : 0;
    }
}

// ---------------- gated aggregation ----------------
__global__ void k_aggw(const float* __restrict__ hn, const int* __restrict__ row_start,
                       const int* __restrict__ csr, const int* __restrict__ in_bit,
                       const int* __restrict__ out_bit, float* __restrict__ aggw, int n) {
    int wid = (blockIdx.x * 256 + threadIdx.x) >> 6;
    int lane = threadIdx.x & 63;
    if (wid >= n) return;
    int d0 = lane * 2;
    float ax = 0.f, ay = 0.f;
    if (in_bit[wid]) {
        int base = row_start[wid], end = row_start[wid + 1];
        for (int off = base; off < end; off += 64) {
            int m = min(64, end - off);
            int myu = 0, myb = 0;
            if (lane < m) { myu = csr[off + lane]; myb = out_bit[myu]; }
            for (int i = 0; i < m; i++) {
                int b = __shfl(myb, i);
                if (b) {
                    int u = __shfl(myu, i);
                    float2 t = *(const float2*)(hn + (size_t)u * DIM + d0);
                    ax += t.x; ay += t.y;
                }
            }
        }
    }
    float2 o2; o2.x = ax; o2.y = ay;
    ((float2*)(aggw + (size_t)wid * DIM))[lane] = o2;
}

// ---------------- node-state bookkeeping ----------------
__global__ void k_state_edges(const int* __restrict__ ei, int E,
                              const int* __restrict__ in_bit, const int* __restrict__ out_bit,
                              int* __restrict__ is_b, int* __restrict__ is_l) {
    int e = blockIdx.x * 256 + threadIdx.x;
    if (e < E) {
        int u = ei[e], v = ei[E + e];
        if (in_bit[v] & out_bit[u]) { is_b[u] = 1; is_l[v] = 1; }  // benign races: same value
    }
}

__global__ void k_states_out(const int* __restrict__ is_b, const int* __restrict__ is_l,
                             float* __restrict__ out_states, int n) {
    int i = blockIdx.x * 256 + threadIdx.x;
    if (i < n) out_states[i] = (float)(3 - 2 * is_b[i] - is_l[i]);
}

// ---------------- GEMM: out = [skip +] relu(A@W1 [+ B@W2] + bias) ----------------
template <int HAS_B, int SKIP>
__global__ void k_gemm(const float* __restrict__ A, const float* __restrict__ W1,
                       const float* __restrict__ B, const float* __restrict__ W2,
                       const float* __restrict__ bias, float* __restrict__ out, int n) {
    __shared__ float sW[32][128];
    __shared__ float sA[64][33];
    int tid = threadIdx.x;
    int rowBase = blockIdx.x * 64;
    int ty = tid >> 4, tx = tid & 15;
    float acc[4][8];
#pragma unroll
    for (int i = 0; i < 4; i++)
#pragma unroll
        for (int j = 0; j < 8; j++) acc[i][j] = 0.f;

    for (int p = 0; p < 1 + HAS_B; p++) {
        const float* Ap = p ? B : A;
        const float* Wp = p ? W2 : W1;
        for (int kc = 0; kc < DIM; kc += 32) {
            __syncthreads();
            {   // stage W chunk: 32x128
                const float4* src = (const float4*)(Wp + kc * DIM);
                float4* dst = (float4*)(&sW[0][0]);
#pragma unroll
                for (int i = 0; i < 4; i++) dst[tid + i * 256] = src[tid + i * 256];
            }
            {   // stage A tile: 64 rows x 32 cols
                int r = tid >> 3, c4 = (tid & 7) * 4;
                float4 v0 = (rowBase + r < n)
                    ? *(const float4*)(Ap + (size_t)(rowBase + r) * DIM + kc + c4)
                    : make_float4(0.f, 0.f, 0.f, 0.f);
                float4 v1 = (rowBase + r + 32 < n)
                    ? *(const float4*)(Ap + (size_t)(rowBase + r + 32) * DIM + kc + c4)
                    : make_float4(0.f, 0.f, 0.f, 0.f);
                sA[r][c4 + 0] = v0.x; sA[r][c4 + 1] = v0.y; sA[r][c4 + 2] = v0.z; sA[r][c4 + 3] = v0.w;
                sA[r + 32][c4 + 0] = v1.x; sA[r + 32][c4 + 1] = v1.y; sA[r + 32][c4 + 2] = v1.z; sA[r + 32][c4 + 3] = v1.w;
            }
            __syncthreads();
#pragma unroll
            for (int kk = 0; kk < 32; kk++) {
                float a0 = sA[ty][kk], a1 = sA[ty + 16][kk], a2 = sA[ty + 32][kk], a3 = sA[ty + 48][kk];
                const float* wr = &sW[kk][tx * 8];
                float w[8];
#pragma unroll
                for (int j = 0; j < 8; j++) w[j] = wr[j];
#pragma unroll
                for (int j = 0; j < 8; j++) {
                    acc[0][j] += a0 * w[j];
                    acc[1][j] += a1 * w[j];
                    acc[2][j] += a2 * w[j];
                    acc[3][j] += a3 * w[j];
                }
            }
        }
    }
#pragma unroll
    for (int i = 0; i < 4; i++) {
        int r = rowBase + ty + i * 16;
        if (r < n) {
#pragma unroll
            for (int j = 0; j < 8; j++) {
                int c = tx * 8 + j;
                float val = acc[i][j] + bias[c];
                val = fmaxf(val, 0.f);
                if (SKIP) val += A[(size_t)r * DIM + c];
                out[(size_t)r * DIM + c] = val;
            }
        }
    }
}

// ---------------- final LN + decoder ----------------
__global__ void k_final(const float* __restrict__ h, const float* __restrict__ gg,
                        const float* __restrict__ bb, const float* __restrict__ Wdec,
                        const float* __restrict__ bdec, float* __restrict__ out, int n) {
    __shared__ float sWd[NCLS * DIM];  // transposed [c][d]
    int tid = threadIdx.x;
    for (int i = tid; i < NCLS * DIM; i += 256) {
        int d = i / NCLS, c = i % NCLS;
        sWd[c * DIM + d] = Wdec[i];
    }
    __syncthreads();
    int wid = (blockIdx.x * 256 + threadIdx.x) >> 6;
    int lane = threadIdx.x & 63;
    if (wid >= n) return;
    int d0 = lane * 2;
    float2 v = ((const float2*)(h + (size_t)wid * DIM))[lane];
    float s = v.x + v.y, q = v.x * v.x + v.y * v.y;
#pragma unroll
    for (int o = 32; o; o >>= 1) { s += __shfl_xor(s, o); q += __shfl_xor(q, o); }
    float m = s * (1.f / DIM);
    float var = q * (1.f / DIM) - m * m;
    float inv = rsqrtf(var + 1e-5f);
    float2 g2 = ((const float2*)gg)[lane], b2 = ((const float2*)bb)[lane];
    float hx = (v.x - m) * inv * g2.x + b2.x;
    float hy = (v.y - m) * inv * g2.y + b2.y;
    float p[NCLS];
#pragma unroll
    for (int c = 0; c < NCLS; c++) {
        float2 w = *(const float2*)(&sWd[c * DIM + d0]);
        p[c] = hx * w.x + hy * w.y;
    }
#pragma unroll
    for (int o = 32; o; o >>= 1)
#pragma unroll
        for (int c = 0; c < NCLS; c++) p[c] += __shfl_xor(p[c], o);
    if (lane == 0) {
#pragma unroll
        for (int c = 0; c < NCLS; c++) out[(size_t)wid * NCLS + c] = p[c] + bdec[c];
    }
}

// ---------------- launcher ----------------
extern "C" void kernel_launch(void* const* d_in, const int* in_sizes, int n_in,
                              void* d_out, int out_size, void* d_ws, size_t ws_size,
                              hipStream_t stream) {
    const float* x      = (const float*)d_in[0];
    const int*   ei     = (const int*)d_in[1];
    const float* W_enc  = (const float*)d_in[2];
    const float* b_enc  = (const float*)d_in[3];
    const float* ln_g   = (const float*)d_in[4];
    const float* ln_b   = (const float*)d_in[5];
    const float* Wr     = (const float*)d_in[6];
    const float* Wn     = (const float*)d_in[7];
    const float* bl     = (const float*)d_in[8];
    const float* Wair   = (const float*)d_in[9];
    const float* Wain   = (const float*)d_in[10];
    const float* bain   = (const float*)d_in[11];
    const float* Waor   = (const float*)d_in[12];
    const float* Waon   = (const float*)d_in[13];
    const float* baon   = (const float*)d_in[14];
    const float* W_dec  = (const float*)d_in[15];
    const float* b_dec  = (const float*)d_in[16];
    const float* gin    = (const float*)d_in[17];
    const float* gout   = (const float*)d_in[18];

    int n = in_sizes[0] / DIM;
    int E = in_sizes[1] / 2;
    const int L = 3;

    char* wsp = (char*)d_ws;
    auto alloc = [&](size_t bytes) { char* p = wsp; wsp += (bytes + 255) / 256 * 256; return p; };
    float* h    = (float*)alloc((size_t)n * DIM * 4);
    float* hn   = (float*)alloc((size_t)n * DIM * 4);
    float* aggw = (float*)alloc((size_t)n * DIM * 4);
    int* deg       = (int*)alloc((size_t)n * 4);
    int* row_start = (int*)alloc((size_t)(n + 1) * 4);
    int* cursor    = (int*)alloc((size_t)n * 4);
    int* csr       = (int*)alloc((size_t)E * 4);
    int* in_bit    = (int*)alloc((size_t)n * 4);
    int* out_bit   = (int*)alloc((size_t)n * 4);
    int* is_bl     = (int*)alloc((size_t)2 * n * 4);
    int* is_b = is_bl;
    int* is_l = is_bl + n;

    float* out_res    = (float*)d_out;                 // [n,10]
    float* out_states = out_res + (size_t)n * NCLS;    // [L,n] as float

    int ebl = (E + 255) / 256;
    int nbl = (n + 255) / 256;
    int wbl = (n + 3) / 4;       // 4 waves (nodes) per 256-thread block
    int gbl = (n + 63) / 64;

    hipMemsetAsync(deg, 0, (size_t)n * 4, stream);
    k_hist<<<ebl, 256, 0, stream>>>(ei, E, deg);
    k_scan<<<1, 256, 0, stream>>>(deg, row_start, cursor, n, E);
    k_fill<<<ebl, 256, 0, stream>>>(ei, E, cursor, csr);

    k_gemm<0, 0><<<gbl, 256, 0, stream>>>(x, W_enc, nullptr, nullptr, b_enc, h, n);

    for (int l = 0; l < L; l++) {
        k_ln<<<wbl, 256, 0, stream>>>(h, ln_g, ln_b, hn, n);
        k_action<<<wbl, 256, 0, stream>>>(hn, row_start, csr, Wair, Wain, bain,
                                          Waor, Waon, baon,
                                          gin + (size_t)l * n * 2, gout + (size_t)l * n * 2,
                                          in_bit, out_bit, n);
        hipMemsetAsync(is_bl, 0, (size_t)2 * n * 4, stream);
        k_state_edges<<<ebl, 256, 0, stream>>>(ei, E, in_bit, out_bit, is_b, is_l);
        k_states_out<<<nbl, 256, 0, stream>>>(is_b, is_l, out_states + (size_t)l * n, n);
        k_aggw<<<wbl, 256, 0, stream>>>(hn, row_start, csr, in_bit, out_bit, aggw, n);
        k_gemm<1, 1><<<gbl, 256, 0, stream>>>(hn, Wr + (size_t)l * DIM * DIM,
                                              aggw, Wn + (size_t)l * DIM * DIM,
                                              bl + (size_t)l * DIM, h, n);
    }
    k_final<<<wbl, 256, 0, stream>>>(h, ln_g, ln_b, W_dec, b_dec, out_res, n);
}

// Round 2
// 683.905 us; speedup vs baseline: 1.2501x; 1.2501x over previous
//
#include <hip/hip_runtime.h>

#define DIM 128
#define NCLS 10

// ---------------- CSR build ----------------
__global__ void k_hist(const int* __restrict__ ei, int E, int* __restrict__ deg) {
    int e = blockIdx.x * 256 + threadIdx.x;
    if (e < E) atomicAdd(&deg[ei[E + e]], 1);   // v = ei[1][e]
}

// pass 1: per-block (1024 elems) local exclusive scan into row_start, block total to bsum
__global__ void k_scan1(const int* __restrict__ deg, int* __restrict__ row_start,
                        int* __restrict__ bsum, int n) {
    int tid = threadIdx.x;
    int base = blockIdx.x * 1024 + tid * 4;
    int v0 = 0, v1 = 0, v2 = 0, v3 = 0;
    if (base + 3 < n) {
        int4 t = *(const int4*)(deg + base);
        v0 = t.x; v1 = t.y; v2 = t.z; v3 = t.w;
    } else {
        if (base + 0 < n) v0 = deg[base + 0];
        if (base + 1 < n) v1 = deg[base + 1];
        if (base + 2 < n) v2 = deg[base + 2];
        if (base + 3 < n) v3 = deg[base + 3];
    }
    int s = v0 + v1 + v2 + v3;
    int lane = tid & 63, w = tid >> 6;
    int inc = s;
#pragma unroll
    for (int o = 1; o < 64; o <<= 1) {
        int t = __shfl_up(inc, o);
        if (lane >= o) inc += t;
    }
    __shared__ int wsum[4];
    if (lane == 63) wsum[w] = inc;
    __syncthreads();
    int woff = 0;
    for (int i = 0; i < w; i++) woff += wsum[i];
    int run = woff + inc - s;   // exclusive prefix for this thread's first elem
    if (base + 0 < n) row_start[base + 0] = run; run += v0;
    if (base + 1 < n) row_start[base + 1] = run; run += v1;
    if (base + 2 < n) row_start[base + 2] = run; run += v2;
    if (base + 3 < n) row_start[base + 3] = run;
    if (tid == 0) bsum[blockIdx.x] = wsum[0] + wsum[1] + wsum[2] + wsum[3];
}

// pass 2: exclusive scan of block sums (nb <= 64 fast path)
__global__ void k_scan2(int* __restrict__ bsum, int nb) {
    int tid = threadIdx.x;
    if (nb <= 64) {
        int v = (tid < nb) ? bsum[tid] : 0;
        int inc = v;
#pragma unroll
        for (int o = 1; o < 64; o <<= 1) {
            int t = __shfl_up(inc, o);
            if (tid >= o) inc += t;
        }
        if (tid < nb) bsum[tid] = inc - v;
    } else if (tid == 0) {
        int acc = 0;
        for (int i = 0; i < nb; i++) { int t = bsum[i]; bsum[i] = acc; acc += t; }
    }
}

// pass 3: add block offsets, init cursor, set sentinel
__global__ void k_scan3(int* __restrict__ row_start, int* __restrict__ cursor,
                        const int* __restrict__ bsum, int n, int E) {
    int i = blockIdx.x * 256 + threadIdx.x;
    if (i < n) {
        int r = row_start[i] + bsum[i >> 10];
        row_start[i] = r;
        cursor[i] = r;
    }
    if (i == n) row_start[n] = E;
}

__global__ void k_fill(const int* __restrict__ ei, int E, int* __restrict__ cursor,
                       int* __restrict__ csr) {
    int e = blockIdx.x * 256 + threadIdx.x;
    if (e < E) {
        int u = ei[e], v = ei[E + e];
        int pos = atomicAdd(&cursor[v], 1);
        csr[pos] = u;
    }
}

// ---------------- agg gather + action nets (agg never materialized) ----------------
__global__ void k_action(const float* __restrict__ hn, const int* __restrict__ row_start,
                         const int* __restrict__ csr,
                         const float* __restrict__ Wair, const float* __restrict__ Wain,
                         const float* __restrict__ bain,
                         const float* __restrict__ Waor, const float* __restrict__ Waon,
                         const float* __restrict__ baon,
                         const float* __restrict__ gin_l, const float* __restrict__ gout_l,
                         int* __restrict__ in_bit, int* __restrict__ out_bit, int n) {
    int wid = (blockIdx.x * 256 + threadIdx.x) >> 6;
    int lane = threadIdx.x & 63;
    if (wid >= n) return;
    int d0 = lane * 2;
    int base = row_start[wid], end = row_start[wid + 1];
    double ax = 0.0, ay = 0.0;
    for (int off = base; off < end; off += 64) {
        int m = min(64, end - off);
        int myu = (lane < m) ? csr[off + lane] : 0;
        for (int i = 0; i < m; i++) {
            int u = __shfl(myu, i);
            float2 t = *(const float2*)(hn + (size_t)u * DIM + d0);
            ax += t.x; ay += t.y;
        }
    }
    float2 hx = *(const float2*)(hn + (size_t)wid * DIM + d0);
    float4 wir = *(const float4*)(Wair + d0 * 2);
    float4 win = *(const float4*)(Wain + d0 * 2);
    float4 wor = *(const float4*)(Waor + d0 * 2);
    float4 won = *(const float4*)(Waon + d0 * 2);
    float axf = (float)ax, ayf = (float)ay;
    float pi0 = hx.x * wir.x + hx.y * wir.z + axf * win.x + ayf * win.z;
    float pi1 = hx.x * wir.y + hx.y * wir.w + axf * win.y + ayf * win.w;
    float po0 = hx.x * wor.x + hx.y * wor.z + axf * won.x + ayf * won.z;
    float po1 = hx.x * wor.y + hx.y * wor.w + axf * won.y + ayf * won.w;
#pragma unroll
    for (int o = 32; o; o >>= 1) {
        pi0 += __shfl_xor(pi0, o); pi1 += __shfl_xor(pi1, o);
        po0 += __shfl_xor(po0, o); po1 += __shfl_xor(po1, o);
    }
    if (lane == 0) {
        float li0 = pi0 + bain[0] + gin_l[(size_t)wid * 2 + 0];
        float li1 = pi1 + bain[1] + gin_l[(size_t)wid * 2 + 1];
        float lo0 = po0 + baon[0] + gout_l[(size_t)wid * 2 + 0];
        float lo1 = po1 + baon[1] + gout_l[(size_t)wid * 2 + 1];
        in_bit[wid]  = (li0 >= li1) ? 1 : 0;  // argmax==0 on tie
        out_bit[wid] = (lo0 >= lo1) ? 1 : 0;
    }
}

// ---------------- gated aggregation ----------------
__global__ void k_aggw(const float* __restrict__ hn, const int* __restrict__ row_start,
                       const int* __restrict__ csr, const int* __restrict__ in_bit,
                       const int* __restrict__ out_bit, float* __restrict__ aggw, int n) {
    int wid = (blockIdx.x * 256 + threadIdx.x) >> 6;
    int lane = threadIdx.x & 63;
    if (wid >= n) return;
    int d0 = lane * 2;
    float ax = 0.f, ay = 0.f;
    if (in_bit[wid]) {
        int base = row_start[wid], end = row_start[wid + 1];
        for (int off = base; off < end; off += 64) {
            int m = min(64, end - off);
            int myu = 0, myb = 0;
            if (lane < m) { myu = csr[off + lane]; myb = out_bit[myu]; }
            for (int i = 0; i < m; i++) {
                int b = __shfl(myb, i);
                if (b) {
                    int u = __shfl(myu, i);
                    float2 t = *(const float2*)(hn + (size_t)u * DIM + d0);
                    ax += t.x; ay += t.y;
                }
            }
        }
    }
    float2 o2; o2.x = ax; o2.y = ay;
    ((float2*)(aggw + (size_t)wid * DIM))[lane] = o2;
}

// ---------------- node-state bookkeeping ----------------
__global__ void k_state_edges(const int* __restrict__ ei, int E,
                              const int* __restrict__ in_bit, const int* __restrict__ out_bit,
                              int* __restrict__ is_b, int* __restrict__ is_l) {
    int e = blockIdx.x * 256 + threadIdx.x;
    if (e < E) {
        int u = ei[e], v = ei[E + e];
        if (in_bit[v] & out_bit[u]) { is_b[u] = 1; is_l[v] = 1; }  // benign races: same value
    }
}

__global__ void k_states_out(const int* __restrict__ is_b, const int* __restrict__ is_l,
                             float* __restrict__ out_states, int n) {
    int i = blockIdx.x * 256 + threadIdx.x;
    if (i < n) out_states[i] = (float)(3 - 2 * is_b[i] - is_l[i]);
}

// ---------------- GEMM: hn_out = [LN]( [A +] relu(A@W1 [+ B@W2] + bias) ) ----------------
// Thread cols: {tx*4..tx*4+3} and {64+tx*4..64+tx*4+3}. Rows: ty+16i, i<4.
// A row's 128 cols live in the 16 lanes sharing ty -> shfl_xor(1,2,4,8) row reduce for LN.
// In-place safe (out==A): all global reads of A precede the final __syncthreads.
template <int HAS_B, int SKIP, int DO_LN>
__global__ void k_gemm(const float* __restrict__ A, const float* __restrict__ W1,
                       const float* __restrict__ B, const float* __restrict__ W2,
                       const float* __restrict__ bias,
                       const float* __restrict__ ln_g, const float* __restrict__ ln_b,
                       float* __restrict__ out, int n) {
    __shared__ float sW[32][128];
    __shared__ float sA[64][36];   // stride 36: 16B-aligned rows, conflict-free b128 reads
    int tid = threadIdx.x;
    int rowBase = blockIdx.x * 64;
    int ty = tid >> 4, tx = tid & 15;
    int c0 = tx * 4, c1 = 64 + tx * 4;
    float acc[4][8];
#pragma unroll
    for (int i = 0; i < 4; i++)
#pragma unroll
        for (int j = 0; j < 8; j++) acc[i][j] = 0.f;

    for (int p = 0; p < 1 + HAS_B; p++) {
        const float* Ap = p ? B : A;
        const float* Wp = p ? W2 : W1;
        for (int kc = 0; kc < DIM; kc += 32) {
            __syncthreads();
            {   // stage W chunk: 32x128
                const float4* src = (const float4*)(Wp + kc * DIM);
                float4* dst = (float4*)(&sW[0][0]);
#pragma unroll
                for (int i = 0; i < 4; i++) dst[tid + i * 256] = src[tid + i * 256];
            }
            {   // stage A tile: 64 rows x 32 cols
                int r = tid >> 3, c4 = (tid & 7) * 4;
                float4 v0 = (rowBase + r < n)
                    ? *(const float4*)(Ap + (size_t)(rowBase + r) * DIM + kc + c4)
                    : make_float4(0.f, 0.f, 0.f, 0.f);
                float4 v1 = (rowBase + r + 32 < n)
                    ? *(const float4*)(Ap + (size_t)(rowBase + r + 32) * DIM + kc + c4)
                    : make_float4(0.f, 0.f, 0.f, 0.f);
                *(float4*)&sA[r][c4] = v0;
                *(float4*)&sA[r + 32][c4] = v1;
            }
            __syncthreads();
#pragma unroll
            for (int kk = 0; kk < 32; kk += 4) {
                float4 a0 = *(const float4*)&sA[ty][kk];
                float4 a1 = *(const float4*)&sA[ty + 16][kk];
                float4 a2 = *(const float4*)&sA[ty + 32][kk];
                float4 a3 = *(const float4*)&sA[ty + 48][kk];
                float a0v[4] = {a0.x, a0.y, a0.z, a0.w};
                float a1v[4] = {a1.x, a1.y, a1.z, a1.w};
                float a2v[4] = {a2.x, a2.y, a2.z, a2.w};
                float a3v[4] = {a3.x, a3.y, a3.z, a3.w};
#pragma unroll
                for (int q = 0; q < 4; q++) {
                    float4 w0 = *(const float4*)&sW[kk + q][c0];
                    float4 w1 = *(const float4*)&sW[kk + q][c1];
                    float wv[8] = {w0.x, w0.y, w0.z, w0.w, w1.x, w1.y, w1.z, w1.w};
#pragma unroll
                    for (int j = 0; j < 8; j++) {
                        acc[0][j] += a0v[q] * wv[j];
                        acc[1][j] += a1v[q] * wv[j];
                        acc[2][j] += a2v[q] * wv[j];
                        acc[3][j] += a3v[q] * wv[j];
                    }
                }
            }
        }
    }

    float4 bias0 = *(const float4*)&bias[c0];
    float4 bias1 = *(const float4*)&bias[c1];
    float bv[8] = {bias0.x, bias0.y, bias0.z, bias0.w, bias1.x, bias1.y, bias1.z, bias1.w};
    float gv[8], bbv[8];
    if (DO_LN) {
        float4 g0 = *(const float4*)&ln_g[c0];
        float4 g1 = *(const float4*)&ln_g[c1];
        float4 lb0 = *(const float4*)&ln_b[c0];
        float4 lb1 = *(const float4*)&ln_b[c1];
        gv[0]=g0.x; gv[1]=g0.y; gv[2]=g0.z; gv[3]=g0.w; gv[4]=g1.x; gv[5]=g1.y; gv[6]=g1.z; gv[7]=g1.w;
        bbv[0]=lb0.x; bbv[1]=lb0.y; bbv[2]=lb0.z; bbv[3]=lb0.w; bbv[4]=lb1.x; bbv[5]=lb1.y; bbv[6]=lb1.z; bbv[7]=lb1.w;
    }

#pragma unroll
    for (int i = 0; i < 4; i++) {
        int r = rowBase + ty + i * 16;
        if (r >= n) continue;   // all 16 lanes of a row group share r -> uniform
        float v[8];
        if (SKIP) {
            float4 s0 = *(const float4*)(A + (size_t)r * DIM + c0);
            float4 s1 = *(const float4*)(A + (size_t)r * DIM + c1);
            float sv[8] = {s0.x, s0.y, s0.z, s0.w, s1.x, s1.y, s1.z, s1.w};
#pragma unroll
            for (int j = 0; j < 8; j++) v[j] = fmaxf(acc[i][j] + bv[j], 0.f) + sv[j];
        } else {
#pragma unroll
            for (int j = 0; j < 8; j++) v[j] = fmaxf(acc[i][j] + bv[j], 0.f);
        }
        if (DO_LN) {
            float s = 0.f, q = 0.f;
#pragma unroll
            for (int j = 0; j < 8; j++) { s += v[j]; q += v[j] * v[j]; }
#pragma unroll
            for (int o = 1; o < 16; o <<= 1) { s += __shfl_xor(s, o); q += __shfl_xor(q, o); }
            float m = s * (1.f / DIM);
            float var = q * (1.f / DIM) - m * m;
            float inv = rsqrtf(var + 1e-5f);
#pragma unroll
            for (int j = 0; j < 8; j++) v[j] = (v[j] - m) * inv * gv[j] + bbv[j];
        }
        float4 o0 = make_float4(v[0], v[1], v[2], v[3]);
        float4 o1 = make_float4(v[4], v[5], v[6], v[7]);
        *(float4*)(out + (size_t)r * DIM + c0) = o0;
        *(float4*)(out + (size_t)r * DIM + c1) = o1;
    }
}

// ---------------- decoder (input already LayerNorm'd) ----------------
__global__ void k_final(const float* __restrict__ hn, const float* __restrict__ Wdec,
                        const float* __restrict__ bdec, float* __restrict__ out, int n) {
    __shared__ float sWd[NCLS * DIM];  // transposed [c][d]
    int tid = threadIdx.x;
    for (int i = tid; i < NCLS * DIM; i += 256) {
        int d = i / NCLS, c = i % NCLS;
        sWd[c * DIM + d] = Wdec[i];
    }
    __syncthreads();
    int wid = (blockIdx.x * 256 + threadIdx.x) >> 6;
    int lane = threadIdx.x & 63;
    if (wid >= n) return;
    int d0 = lane * 2;
    float2 v = ((const float2*)(hn + (size_t)wid * DIM))[lane];
    float p[NCLS];
#pragma unroll
    for (int c = 0; c < NCLS; c++) {
        float2 w = *(const float2*)(&sWd[c * DIM + d0]);
        p[c] = v.x * w.x + v.y * w.y;
    }
#pragma unroll
    for (int o = 32; o; o >>= 1)
#pragma unroll
        for (int c = 0; c < NCLS; c++) p[c] += __shfl_xor(p[c], o);
    if (lane == 0) {
#pragma unroll
        for (int c = 0; c < NCLS; c++) out[(size_t)wid * NCLS + c] = p[c] + bdec[c];
    }
}

// ---------------- launcher ----------------
extern "C" void kernel_launch(void* const* d_in, const int* in_sizes, int n_in,
                              void* d_out, int out_size, void* d_ws, size_t ws_size,
                              hipStream_t stream) {
    const float* x      = (const float*)d_in[0];
    const int*   ei     = (const int*)d_in[1];
    const float* W_enc  = (const float*)d_in[2];
    const float* b_enc  = (const float*)d_in[3];
    const float* ln_g   = (const float*)d_in[4];
    const float* ln_b   = (const float*)d_in[5];
    const float* Wr     = (const float*)d_in[6];
    const float* Wn     = (const float*)d_in[7];
    const float* bl     = (const float*)d_in[8];
    const float* Wair   = (const float*)d_in[9];
    const float* Wain   = (const float*)d_in[10];
    const float* bain   = (const float*)d_in[11];
    const float* Waor   = (const float*)d_in[12];
    const float* Waon   = (const float*)d_in[13];
    const float* baon   = (const float*)d_in[14];
    const float* W_dec  = (const float*)d_in[15];
    const float* b_dec  = (const float*)d_in[16];
    const float* gin    = (const float*)d_in[17];
    const float* gout   = (const float*)d_in[18];

    int n = in_sizes[0] / DIM;
    int E = in_sizes[1] / 2;
    const int L = 3;

    char* wsp = (char*)d_ws;
    auto alloc = [&](size_t bytes) { char* p = wsp; wsp += (bytes + 255) / 256 * 256; return p; };
    float* hn   = (float*)alloc((size_t)n * DIM * 4);
    float* aggw = (float*)alloc((size_t)n * DIM * 4);
    int* deg       = (int*)alloc((size_t)n * 4);
    int* row_start = (int*)alloc((size_t)(n + 1) * 4);
    int* cursor    = (int*)alloc((size_t)n * 4);
    int* csr       = (int*)alloc((size_t)E * 4);
    int* in_bit    = (int*)alloc((size_t)n * 4);
    int* out_bit   = (int*)alloc((size_t)n * 4);
    int* bsum      = (int*)alloc((size_t)256 * 4);
    int* is_bl     = (int*)alloc((size_t)2 * n * 4);
    int* is_b = is_bl;
    int* is_l = is_bl + n;

    float* out_res    = (float*)d_out;                 // [n,10]
    float* out_states = out_res + (size_t)n * NCLS;    // [L,n] as float

    int ebl = (E + 255) / 256;
    int nbl = (n + 255) / 256;
    int wbl = (n + 3) / 4;        // 4 waves (nodes) per 256-thread block
    int gbl = (n + 63) / 64;
    int nb  = (n + 1023) / 1024;  // scan blocks

    hipMemsetAsync(deg, 0, (size_t)n * 4, stream);
    k_hist<<<ebl, 256, 0, stream>>>(ei, E, deg);
    k_scan1<<<nb, 256, 0, stream>>>(deg, row_start, bsum, n);
    k_scan2<<<1, 64, 0, stream>>>(bsum, nb);
    k_scan3<<<(n + 256) / 256, 256, 0, stream>>>(row_start, cursor, bsum, n, E);
    k_fill<<<ebl, 256, 0, stream>>>(ei, E, cursor, csr);

    // encoder + fused LN -> hn
    k_gemm<0, 0, 1><<<gbl, 256, 0, stream>>>(x, W_enc, nullptr, nullptr, b_enc,
                                             ln_g, ln_b, hn, n);

    for (int l = 0; l < L; l++) {
        k_action<<<wbl, 256, 0, stream>>>(hn, row_start, csr, Wair, Wain, bain,
                                          Waor, Waon, baon,
                                          gin + (size_t)l * n * 2, gout + (size_t)l * n * 2,
                                          in_bit, out_bit, n);
        hipMemsetAsync(is_bl, 0, (size_t)2 * n * 4, stream);
        k_state_edges<<<ebl, 256, 0, stream>>>(ei, E, in_bit, out_bit, is_b, is_l);
        k_states_out<<<nbl, 256, 0, stream>>>(is_b, is_l, out_states + (size_t)l * n, n);
        k_aggw<<<wbl, 256, 0, stream>>>(hn, row_start, csr, in_bit, out_bit, aggw, n);
        // h_new = hn + relu(hn@Wr + aggw@Wn + bl); then LN -> next hn (in-place)
        k_gemm<1, 1, 1><<<gbl, 256, 0, stream>>>(hn, Wr + (size_t)l * DIM * DIM,
                                                 aggw, Wn + (size_t)l * DIM * DIM,
                                                 bl + (size_t)l * DIM,
                                                 ln_g, ln_b, hn, n);
    }
    k_final<<<wbl, 256, 0, stream>>>(hn, W_dec, b_dec, out_res, n);
}

// Round 3
// 672.018 us; speedup vs baseline: 1.2722x; 1.0177x over previous
//
#include <hip/hip_runtime.h>

#define DIM 128
#define NCLS 10

// ---------------- CSR build ----------------
__global__ void k_hist(const int* __restrict__ ei, int E, int* __restrict__ deg) {
    int e = blockIdx.x * 256 + threadIdx.x;
    if (e < E) atomicAdd(&deg[ei[E + e]], 1);   // v = ei[1][e]
}

// pass 1: per-block (1024 elems) local exclusive scan into row_start, block total to bsum
__global__ void k_scan1(const int* __restrict__ deg, int* __restrict__ row_start,
                        int* __restrict__ bsum, int n) {
    int tid = threadIdx.x;
    int base = blockIdx.x * 1024 + tid * 4;
    int v0 = 0, v1 = 0, v2 = 0, v3 = 0;
    if (base + 3 < n) {
        int4 t = *(const int4*)(deg + base);
        v0 = t.x; v1 = t.y; v2 = t.z; v3 = t.w;
    } else {
        if (base + 0 < n) v0 = deg[base + 0];
        if (base + 1 < n) v1 = deg[base + 1];
        if (base + 2 < n) v2 = deg[base + 2];
        if (base + 3 < n) v3 = deg[base + 3];
    }
    int s = v0 + v1 + v2 + v3;
    int lane = tid & 63, w = tid >> 6;
    int inc = s;
#pragma unroll
    for (int o = 1; o < 64; o <<= 1) {
        int t = __shfl_up(inc, o);
        if (lane >= o) inc += t;
    }
    __shared__ int wsum[4];
    if (lane == 63) wsum[w] = inc;
    __syncthreads();
    int woff = 0;
    for (int i = 0; i < w; i++) woff += wsum[i];
    int run = woff + inc - s;   // exclusive prefix for this thread's first elem
    if (base + 0 < n) row_start[base + 0] = run; run += v0;
    if (base + 1 < n) row_start[base + 1] = run; run += v1;
    if (base + 2 < n) row_start[base + 2] = run; run += v2;
    if (base + 3 < n) row_start[base + 3] = run;
    if (tid == 0) bsum[blockIdx.x] = wsum[0] + wsum[1] + wsum[2] + wsum[3];
}

// pass 2: exclusive scan of block sums (nb <= 64 fast path)
__global__ void k_scan2(int* __restrict__ bsum, int nb) {
    int tid = threadIdx.x;
    if (nb <= 64) {
        int v = (tid < nb) ? bsum[tid] : 0;
        int inc = v;
#pragma unroll
        for (int o = 1; o < 64; o <<= 1) {
            int t = __shfl_up(inc, o);
            if (tid >= o) inc += t;
        }
        if (tid < nb) bsum[tid] = inc - v;
    } else if (tid == 0) {
        int acc = 0;
        for (int i = 0; i < nb; i++) { int t = bsum[i]; bsum[i] = acc; acc += t; }
    }
}

// pass 3: add block offsets, init cursor, set sentinel
__global__ void k_scan3(int* __restrict__ row_start, int* __restrict__ cursor,
                        const int* __restrict__ bsum, int n, int E) {
    int i = blockIdx.x * 256 + threadIdx.x;
    if (i < n) {
        int r = row_start[i] + bsum[i >> 10];
        row_start[i] = r;
        cursor[i] = r;
    }
    if (i == n) row_start[n] = E;
}

__global__ void k_fill(const int* __restrict__ ei, int E, int* __restrict__ cursor,
                       int* __restrict__ csr) {
    int e = blockIdx.x * 256 + threadIdx.x;
    if (e < E) {
        int u = ei[e], v = ei[E + e];
        int pos = atomicAdd(&cursor[v], 1);
        csr[pos] = u;
    }
}

// ---------------- per-node 8-dim projection ----------------
// proj[u][0..3] = hn[u] @ [Wa_in_n | Wa_out_n]   (neighbor part)
// proj[u][4..7] = hn[u] @ [Wa_in_r | Wa_out_r]   (root part)
__global__ void k_proj(const float* __restrict__ hn,
                       const float* __restrict__ Wain, const float* __restrict__ Waon,
                       const float* __restrict__ Wair, const float* __restrict__ Waor,
                       float* __restrict__ proj, int n) {
    int wid = (blockIdx.x * 256 + threadIdx.x) >> 6;
    int lane = threadIdx.x & 63;
    if (wid >= n) return;
    int d0 = lane * 2;
    float2 h2 = *(const float2*)(hn + (size_t)wid * DIM + d0);
    float4 win = *(const float4*)(Wain + d0 * 2);   // rows d0,d0+1 of 128x2
    float4 won = *(const float4*)(Waon + d0 * 2);
    float4 wir = *(const float4*)(Wair + d0 * 2);
    float4 wor = *(const float4*)(Waor + d0 * 2);
    float p[8];
    p[0] = h2.x * win.x + h2.y * win.z;  p[1] = h2.x * win.y + h2.y * win.w;
    p[2] = h2.x * won.x + h2.y * won.z;  p[3] = h2.x * won.y + h2.y * won.w;
    p[4] = h2.x * wir.x + h2.y * wir.z;  p[5] = h2.x * wir.y + h2.y * wir.w;
    p[6] = h2.x * wor.x + h2.y * wor.z;  p[7] = h2.x * wor.y + h2.y * wor.w;
#pragma unroll
    for (int o = 32; o; o >>= 1)
#pragma unroll
        for (int j = 0; j < 8; j++) p[j] += __shfl_xor(p[j], o);
    if (lane == 0) {
        float4 a = make_float4(p[0], p[1], p[2], p[3]);
        float4 b = make_float4(p[4], p[5], p[6], p[7]);
        *(float4*)(proj + (size_t)wid * 8)     = a;
        *(float4*)(proj + (size_t)wid * 8 + 4) = b;
    }
}

// ---------------- action gates: thread per node, gather 16B/neighbor (L2-resident) ----
__global__ void k_action(const float* __restrict__ proj, const int* __restrict__ row_start,
                         const int* __restrict__ csr,
                         const float* __restrict__ bain, const float* __restrict__ baon,
                         const float* __restrict__ gin_l, const float* __restrict__ gout_l,
                         int* __restrict__ in_bit, int* __restrict__ out_bit, int n) {
    int v = blockIdx.x * 256 + threadIdx.x;
    if (v >= n) return;
    int b0 = row_start[v], b1 = row_start[v + 1];
    double a0 = 0.0, a1 = 0.0, a2 = 0.0, a3 = 0.0;
    for (int e = b0; e < b1; e++) {
        int u = csr[e];
        float4 p = *(const float4*)(proj + (size_t)u * 8);
        a0 += p.x; a1 += p.y; a2 += p.z; a3 += p.w;
    }
    float4 r = *(const float4*)(proj + (size_t)v * 8 + 4);
    float2 gi = *(const float2*)(gin_l + (size_t)v * 2);
    float2 go = *(const float2*)(gout_l + (size_t)v * 2);
    float li0 = (float)a0 + r.x + bain[0] + gi.x;
    float li1 = (float)a1 + r.y + bain[1] + gi.y;
    float lo0 = (float)a2 + r.z + baon[0] + go.x;
    float lo1 = (float)a3 + r.w + baon[1] + go.y;
    in_bit[v]  = (li0 >= li1) ? 1 : 0;   // argmax==0 on tie
    out_bit[v] = (lo0 >= lo1) ? 1 : 0;
}

// ---------------- gated aggregation ----------------
__global__ void k_aggw(const float* __restrict__ hn, const int* __restrict__ row_start,
                       const int* __restrict__ csr, const int* __restrict__ in_bit,
                       const int* __restrict__ out_bit, float* __restrict__ aggw, int n) {
    int wid = (blockIdx.x * 256 + threadIdx.x) >> 6;
    int lane = threadIdx.x & 63;
    if (wid >= n) return;
    int d0 = lane * 2;
    float ax = 0.f, ay = 0.f;
    if (in_bit[wid]) {
        int base = row_start[wid], end = row_start[wid + 1];
        for (int off = base; off < end; off += 64) {
            int m = min(64, end - off);
            int myu = 0, myb = 0;
            if (lane < m) { myu = csr[off + lane]; myb = out_bit[myu]; }
            for (int i = 0; i < m; i++) {
                int b = __shfl(myb, i);
                if (b) {
                    int u = __shfl(myu, i);
                    float2 t = *(const float2*)(hn + (size_t)u * DIM + d0);
                    ax += t.x; ay += t.y;
                }
            }
        }
    }
    float2 o2; o2.x = ax; o2.y = ay;
    ((float2*)(aggw + (size_t)wid * DIM))[lane] = o2;
}

// ---------------- node-state bookkeeping ----------------
__global__ void k_state_edges(const int* __restrict__ ei, int E,
                              const int* __restrict__ in_bit, const int* __restrict__ out_bit,
                              int* __restrict__ is_b, int* __restrict__ is_l) {
    int e = blockIdx.x * 256 + threadIdx.x;
    if (e < E) {
        int u = ei[e], v = ei[E + e];
        if (in_bit[v] & out_bit[u]) { is_b[u] = 1; is_l[v] = 1; }  // benign races: same value
    }
}

__global__ void k_states_out(const int* __restrict__ is_b, const int* __restrict__ is_l,
                             float* __restrict__ out_states, int n) {
    int i = blockIdx.x * 256 + threadIdx.x;
    if (i < n) out_states[i] = (float)(3 - 2 * is_b[i] - is_l[i]);
}

// ---------------- GEMM: hn_out = [LN]( [A +] relu(A@W1 [+ B@W2] + bias) ) ----------------
// Double-buffered LDS staging: one barrier per K-chunk, global->reg prefetch of
// chunk t+1 issued right after the barrier, hidden under compute of chunk t.
// In-place safe (out==A): all global reads precede the epilogue writes per thread,
// and blocks touch disjoint row ranges.
template <int HAS_B, int SKIP, int DO_LN>
__global__ void k_gemm(const float* __restrict__ A, const float* __restrict__ W1,
                       const float* __restrict__ B, const float* __restrict__ W2,
                       const float* __restrict__ bias,
                       const float* __restrict__ ln_g, const float* __restrict__ ln_b,
                       float* __restrict__ out, int n) {
    __shared__ float sW[2][32][128];
    __shared__ float sA[2][64][36];   // stride 36: 16B-aligned rows, conflict-free b128
    int tid = threadIdx.x;
    int rowBase = blockIdx.x * 64;
    int ty = tid >> 4, tx = tid & 15;
    int c0 = tx * 4, c1 = 64 + tx * 4;
    const int T = 4 * (1 + HAS_B);

    float acc[4][8];
#pragma unroll
    for (int i = 0; i < 4; i++)
#pragma unroll
        for (int j = 0; j < 8; j++) acc[i][j] = 0.f;

    float4 wreg[4], areg0, areg1;
    int lr = tid >> 3, lc4 = (tid & 7) * 4;

    auto load_chunk = [&](int t) {
        const float* Ap = (HAS_B && (t >> 2)) ? B : A;
        const float* Wp = (HAS_B && (t >> 2)) ? W2 : W1;
        int kc = (t & 3) * 32;
        const float4* src = (const float4*)(Wp + kc * DIM);
#pragma unroll
        for (int i = 0; i < 4; i++) wreg[i] = src[tid + i * 256];
        areg0 = (rowBase + lr < n)
            ? *(const float4*)(Ap + (size_t)(rowBase + lr) * DIM + kc + lc4)
            : make_float4(0.f, 0.f, 0.f, 0.f);
        areg1 = (rowBase + lr + 32 < n)
            ? *(const float4*)(Ap + (size_t)(rowBase + lr + 32) * DIM + kc + lc4)
            : make_float4(0.f, 0.f, 0.f, 0.f);
    };

    load_chunk(0);
    for (int t = 0; t < T; t++) {
        int b = t & 1;
        {   // commit prefetched regs to LDS buffer b
            float4* dst = (float4*)(&sW[b][0][0]);
#pragma unroll
            for (int i = 0; i < 4; i++) dst[tid + i * 256] = wreg[i];
            *(float4*)&sA[b][lr][lc4] = areg0;
            *(float4*)&sA[b][lr + 32][lc4] = areg1;
        }
        __syncthreads();
        if (t + 1 < T) load_chunk(t + 1);   // hidden under compute below
#pragma unroll
        for (int kk = 0; kk < 32; kk += 4) {
            float4 a0 = *(const float4*)&sA[b][ty][kk];
            float4 a1 = *(const float4*)&sA[b][ty + 16][kk];
            float4 a2 = *(const float4*)&sA[b][ty + 32][kk];
            float4 a3 = *(const float4*)&sA[b][ty + 48][kk];
            float a0v[4] = {a0.x, a0.y, a0.z, a0.w};
            float a1v[4] = {a1.x, a1.y, a1.z, a1.w};
            float a2v[4] = {a2.x, a2.y, a2.z, a2.w};
            float a3v[4] = {a3.x, a3.y, a3.z, a3.w};
#pragma unroll
            for (int q = 0; q < 4; q++) {
                float4 w0 = *(const float4*)&sW[b][kk + q][c0];
                float4 w1 = *(const float4*)&sW[b][kk + q][c1];
                float wv[8] = {w0.x, w0.y, w0.z, w0.w, w1.x, w1.y, w1.z, w1.w};
#pragma unroll
                for (int j = 0; j < 8; j++) {
                    acc[0][j] += a0v[q] * wv[j];
                    acc[1][j] += a1v[q] * wv[j];
                    acc[2][j] += a2v[q] * wv[j];
                    acc[3][j] += a3v[q] * wv[j];
                }
            }
        }
    }

    float4 bias0 = *(const float4*)&bias[c0];
    float4 bias1 = *(const float4*)&bias[c1];
    float bv[8] = {bias0.x, bias0.y, bias0.z, bias0.w, bias1.x, bias1.y, bias1.z, bias1.w};
    float gv[8], bbv[8];
    if (DO_LN) {
        float4 g0 = *(const float4*)&ln_g[c0];
        float4 g1 = *(const float4*)&ln_g[c1];
        float4 lb0 = *(const float4*)&ln_b[c0];
        float4 lb1 = *(const float4*)&ln_b[c1];
        gv[0]=g0.x; gv[1]=g0.y; gv[2]=g0.z; gv[3]=g0.w; gv[4]=g1.x; gv[5]=g1.y; gv[6]=g1.z; gv[7]=g1.w;
        bbv[0]=lb0.x; bbv[1]=lb0.y; bbv[2]=lb0.z; bbv[3]=lb0.w; bbv[4]=lb1.x; bbv[5]=lb1.y; bbv[6]=lb1.z; bbv[7]=lb1.w;
    }

#pragma unroll
    for (int i = 0; i < 4; i++) {
        int r = rowBase + ty + i * 16;
        if (r >= n) continue;   // uniform across the 16 lanes sharing ty
        float v[8];
        if (SKIP) {
            float4 s0 = *(const float4*)(A + (size_t)r * DIM + c0);
            float4 s1 = *(const float4*)(A + (size_t)r * DIM + c1);
            float sv[8] = {s0.x, s0.y, s0.z, s0.w, s1.x, s1.y, s1.z, s1.w};
#pragma unroll
            for (int j = 0; j < 8; j++) v[j] = fmaxf(acc[i][j] + bv[j], 0.f) + sv[j];
        } else {
#pragma unroll
            for (int j = 0; j < 8; j++) v[j] = fmaxf(acc[i][j] + bv[j], 0.f);
        }
        if (DO_LN) {
            float s = 0.f, q = 0.f;
#pragma unroll
            for (int j = 0; j < 8; j++) { s += v[j]; q += v[j] * v[j]; }
#pragma unroll
            for (int o = 1; o < 16; o <<= 1) { s += __shfl_xor(s, o); q += __shfl_xor(q, o); }
            float m = s * (1.f / DIM);
            float var = q * (1.f / DIM) - m * m;
            float inv = rsqrtf(var + 1e-5f);
#pragma unroll
            for (int j = 0; j < 8; j++) v[j] = (v[j] - m) * inv * gv[j] + bbv[j];
        }
        *(float4*)(out + (size_t)r * DIM + c0) = make_float4(v[0], v[1], v[2], v[3]);
        *(float4*)(out + (size_t)r * DIM + c1) = make_float4(v[4], v[5], v[6], v[7]);
    }
}

// ---------------- decoder (input already LayerNorm'd) ----------------
__global__ void k_final(const float* __restrict__ hn, const float* __restrict__ Wdec,
                        const float* __restrict__ bdec, float* __restrict__ out, int n) {
    __shared__ float sWd[NCLS * DIM];  // transposed [c][d]
    int tid = threadIdx.x;
    for (int i = tid; i < NCLS * DIM; i += 256) {
        int d = i / NCLS, c = i % NCLS;
        sWd[c * DIM + d] = Wdec[i];
    }
    __syncthreads();
    int wid = (blockIdx.x * 256 + threadIdx.x) >> 6;
    int lane = threadIdx.x & 63;
    if (wid >= n) return;
    int d0 = lane * 2;
    float2 v = ((const float2*)(hn + (size_t)wid * DIM))[lane];
    float p[NCLS];
#pragma unroll
    for (int c = 0; c < NCLS; c++) {
        float2 w = *(const float2*)(&sWd[c * DIM + d0]);
        p[c] = v.x * w.x + v.y * w.y;
    }
#pragma unroll
    for (int o = 32; o; o >>= 1)
#pragma unroll
        for (int c = 0; c < NCLS; c++) p[c] += __shfl_xor(p[c], o);
    if (lane == 0) {
#pragma unroll
        for (int c = 0; c < NCLS; c++) out[(size_t)wid * NCLS + c] = p[c] + bdec[c];
    }
}

// ---------------- launcher ----------------
extern "C" void kernel_launch(void* const* d_in, const int* in_sizes, int n_in,
                              void* d_out, int out_size, void* d_ws, size_t ws_size,
                              hipStream_t stream) {
    const float* x      = (const float*)d_in[0];
    const int*   ei     = (const int*)d_in[1];
    const float* W_enc  = (const float*)d_in[2];
    const float* b_enc  = (const float*)d_in[3];
    const float* ln_g   = (const float*)d_in[4];
    const float* ln_b   = (const float*)d_in[5];
    const float* Wr     = (const float*)d_in[6];
    const float* Wn     = (const float*)d_in[7];
    const float* bl     = (const float*)d_in[8];
    const float* Wair   = (const float*)d_in[9];
    const float* Wain   = (const float*)d_in[10];
    const float* bain   = (const float*)d_in[11];
    const float* Waor   = (const float*)d_in[12];
    const float* Waon   = (const float*)d_in[13];
    const float* baon   = (const float*)d_in[14];
    const float* W_dec  = (const float*)d_in[15];
    const float* b_dec  = (const float*)d_in[16];
    const float* gin    = (const float*)d_in[17];
    const float* gout   = (const float*)d_in[18];

    int n = in_sizes[0] / DIM;
    int E = in_sizes[1] / 2;
    const int L = 3;

    char* wsp = (char*)d_ws;
    auto alloc = [&](size_t bytes) { char* p = wsp; wsp += (bytes + 255) / 256 * 256; return p; };
    float* hn   = (float*)alloc((size_t)n * DIM * 4);
    float* aggw = (float*)alloc((size_t)n * DIM * 4);
    float* proj = (float*)alloc((size_t)n * 8 * 4);
    int* deg       = (int*)alloc((size_t)n * 4);
    int* row_start = (int*)alloc((size_t)(n + 1) * 4);
    int* cursor    = (int*)alloc((size_t)n * 4);
    int* csr       = (int*)alloc((size_t)E * 4);
    int* in_bit    = (int*)alloc((size_t)n * 4);
    int* out_bit   = (int*)alloc((size_t)n * 4);
    int* bsum      = (int*)alloc((size_t)256 * 4);
    int* is_bl     = (int*)alloc((size_t)2 * n * 4);
    int* is_b = is_bl;
    int* is_l = is_bl + n;

    float* out_res    = (float*)d_out;                 // [n,10]
    float* out_states = out_res + (size_t)n * NCLS;    // [L,n] as float

    int ebl = (E + 255) / 256;
    int nbl = (n + 255) / 256;
    int wbl = (n + 3) / 4;        // 4 waves (nodes) per 256-thread block
    int gbl = (n + 63) / 64;
    int nb  = (n + 1023) / 1024;  // scan blocks

    hipMemsetAsync(deg, 0, (size_t)n * 4, stream);
    k_hist<<<ebl, 256, 0, stream>>>(ei, E, deg);
    k_scan1<<<nb, 256, 0, stream>>>(deg, row_start, bsum, n);
    k_scan2<<<1, 64, 0, stream>>>(bsum, nb);
    k_scan3<<<(n + 256) / 256, 256, 0, stream>>>(row_start, cursor, bsum, n, E);
    k_fill<<<ebl, 256, 0, stream>>>(ei, E, cursor, csr);

    // encoder + fused LN -> hn
    k_gemm<0, 0, 1><<<gbl, 256, 0, stream>>>(x, W_enc, nullptr, nullptr, b_enc,
                                             ln_g, ln_b, hn, n);

    for (int l = 0; l < L; l++) {
        k_proj<<<wbl, 256, 0, stream>>>(hn, Wain, Waon, Wair, Waor, proj, n);
        k_action<<<nbl, 256, 0, stream>>>(proj, row_start, csr, bain, baon,
                                          gin + (size_t)l * n * 2, gout + (size_t)l * n * 2,
                                          in_bit, out_bit, n);
        hipMemsetAsync(is_bl, 0, (size_t)2 * n * 4, stream);
        k_state_edges<<<ebl, 256, 0, stream>>>(ei, E, in_bit, out_bit, is_b, is_l);
        k_states_out<<<nbl, 256, 0, stream>>>(is_b, is_l, out_states + (size_t)l * n, n);
        k_aggw<<<wbl, 256, 0, stream>>>(hn, row_start, csr, in_bit, out_bit, aggw, n);
        // h_new = hn + relu(hn@Wr + aggw@Wn + bl); then LN -> next hn (in-place)
        k_gemm<1, 1, 1><<<gbl, 256, 0, stream>>>(hn, Wr + (size_t)l * DIM * DIM,
                                                 aggw, Wn + (size_t)l * DIM * DIM,
                                                 bl + (size_t)l * DIM,
                                                 ln_g, ln_b, hn, n);
    }
    k_final<<<wbl, 256, 0, stream>>>(hn, W_dec, b_dec, out_res, n);
}

// Round 4
// 532.310 us; speedup vs baseline: 1.6061x; 1.2625x over previous
//
#include <hip/hip_runtime.h>

#define DIM 128
#define NCLS 10

// ---------------- CSR build ----------------
__global__ void k_hist(const int* __restrict__ ei, int E, int* __restrict__ deg) {
    int e = blockIdx.x * 256 + threadIdx.x;
    if (e < E) atomicAdd(&deg[ei[E + e]], 1);   // v = ei[1][e]
}

__global__ void k_scan1(const int* __restrict__ deg, int* __restrict__ row_start,
                        int* __restrict__ bsum, int n) {
    int tid = threadIdx.x;
    int base = blockIdx.x * 1024 + tid * 4;
    int v0 = 0, v1 = 0, v2 = 0, v3 = 0;
    if (base + 3 < n) {
        int4 t = *(const int4*)(deg + base);
        v0 = t.x; v1 = t.y; v2 = t.z; v3 = t.w;
    } else {
        if (base + 0 < n) v0 = deg[base + 0];
        if (base + 1 < n) v1 = deg[base + 1];
        if (base + 2 < n) v2 = deg[base + 2];
        if (base + 3 < n) v3 = deg[base + 3];
    }
    int s = v0 + v1 + v2 + v3;
    int lane = tid & 63, w = tid >> 6;
    int inc = s;
#pragma unroll
    for (int o = 1; o < 64; o <<= 1) {
        int t = __shfl_up(inc, o);
        if (lane >= o) inc += t;
    }
    __shared__ int wsum[4];
    if (lane == 63) wsum[w] = inc;
    __syncthreads();
    int woff = 0;
    for (int i = 0; i < w; i++) woff += wsum[i];
    int run = woff + inc - s;
    if (base + 0 < n) row_start[base + 0] = run; run += v0;
    if (base + 1 < n) row_start[base + 1] = run; run += v1;
    if (base + 2 < n) row_start[base + 2] = run; run += v2;
    if (base + 3 < n) row_start[base + 3] = run;
    if (tid == 0) bsum[blockIdx.x] = wsum[0] + wsum[1] + wsum[2] + wsum[3];
}

__global__ void k_scan2(int* __restrict__ bsum, int nb) {
    int tid = threadIdx.x;
    if (nb <= 64) {
        int v = (tid < nb) ? bsum[tid] : 0;
        int inc = v;
#pragma unroll
        for (int o = 1; o < 64; o <<= 1) {
            int t = __shfl_up(inc, o);
            if (tid >= o) inc += t;
        }
        if (tid < nb) bsum[tid] = inc - v;
    } else if (tid == 0) {
        int acc = 0;
        for (int i = 0; i < nb; i++) { int t = bsum[i]; bsum[i] = acc; acc += t; }
    }
}

__global__ void k_scan3(int* __restrict__ row_start, int* __restrict__ cursor,
                        const int* __restrict__ bsum, int n, int E) {
    int i = blockIdx.x * 256 + threadIdx.x;
    if (i < n) {
        int r = row_start[i] + bsum[i >> 10];
        row_start[i] = r;
        cursor[i] = r;
    }
    if (i == n) row_start[n] = E;
}

__global__ void k_fill(const int* __restrict__ ei, int E, int* __restrict__ cursor,
                       int* __restrict__ csr) {
    int e = blockIdx.x * 256 + threadIdx.x;
    if (e < E) {
        int u = ei[e], v = ei[E + e];
        int pos = atomicAdd(&cursor[v], 1);
        csr[pos] = u;
    }
}

// ---------------- action gates: thread per node, 16B/neighbor gather ----------------
// Also zeroes is_b/is_l (consumed by k_state_edges which runs next on the stream).
__global__ void k_action(const float* __restrict__ proj, const int* __restrict__ row_start,
                         const int* __restrict__ csr,
                         const float* __restrict__ bain, const float* __restrict__ baon,
                         const float* __restrict__ gin_l, const float* __restrict__ gout_l,
                         int* __restrict__ in_bit, int* __restrict__ out_bit,
                         int* __restrict__ is_b, int* __restrict__ is_l, int n) {
    int v = blockIdx.x * 256 + threadIdx.x;
    if (v >= n) return;
    is_b[v] = 0; is_l[v] = 0;
    int b0 = row_start[v], b1 = row_start[v + 1];
    double a0 = 0.0, a1 = 0.0, a2 = 0.0, a3 = 0.0;
    for (int e = b0; e < b1; e++) {
        int u = csr[e];
        float4 p = *(const float4*)(proj + (size_t)u * 8);
        a0 += p.x; a1 += p.y; a2 += p.z; a3 += p.w;
    }
    float4 r = *(const float4*)(proj + (size_t)v * 8 + 4);
    float2 gi = *(const float2*)(gin_l + (size_t)v * 2);
    float2 go = *(const float2*)(gout_l + (size_t)v * 2);
    float li0 = (float)a0 + r.x + bain[0] + gi.x;
    float li1 = (float)a1 + r.y + bain[1] + gi.y;
    float lo0 = (float)a2 + r.z + baon[0] + go.x;
    float lo1 = (float)a3 + r.w + baon[1] + go.y;
    in_bit[v]  = (li0 >= li1) ? 1 : 0;   // argmax==0 on tie
    out_bit[v] = (lo0 >= lo1) ? 1 : 0;
}

// ---------------- node-state edge pass ----------------
__global__ void k_state_edges(const int* __restrict__ ei, int E,
                              const int* __restrict__ in_bit, const int* __restrict__ out_bit,
                              int* __restrict__ is_b, int* __restrict__ is_l) {
    int e = blockIdx.x * 256 + threadIdx.x;
    if (e < E) {
        int u = ei[e], v = ei[E + e];
        if (in_bit[v] & out_bit[u]) { is_b[u] = 1; is_l[v] = 1; }  // benign races: same value
    }
}

// ---------------- gated aggregation (ballot over gated neighbors) + states out ------
__global__ void k_aggw(const float* __restrict__ hn, const int* __restrict__ row_start,
                       const int* __restrict__ csr, const int* __restrict__ in_bit,
                       const int* __restrict__ out_bit,
                       const int* __restrict__ is_b, const int* __restrict__ is_l,
                       float* __restrict__ aggw, float* __restrict__ out_states_l, int n) {
    int wid = (blockIdx.x * 256 + threadIdx.x) >> 6;
    int lane = threadIdx.x & 63;
    if (wid >= n) return;
    if (lane == 0)
        out_states_l[wid] = (float)(3 - 2 * is_b[wid] - is_l[wid]);
    int d0 = lane * 2;
    float ax = 0.f, ay = 0.f;
    if (in_bit[wid]) {
        int base = row_start[wid], end = row_start[wid + 1];
        for (int off = base; off < end; off += 64) {
            int m = min(64, end - off);
            int myu = 0, myb = 0;
            if (lane < m) { myu = csr[off + lane]; myb = out_bit[myu]; }
            unsigned long long mask = __ballot(myb != 0);
            while (mask) {
                int i = __ffsll((unsigned long long)mask) - 1;
                mask &= mask - 1;
                int u = __shfl(myu, i);
                float2 t = *(const float2*)(hn + (size_t)u * DIM + d0);
                ax += t.x; ay += t.y;
            }
        }
    }
    ((float2*)(aggw + (size_t)wid * DIM))[lane] = make_float2(ax, ay);
}

// ---------------- GEMM: hn_out = [LN]( [A +] relu(A@W1 [+ B@W2] + bias) ) ------------
// 32-row x 128-col tile, 256 threads (TM=2, TN=8) -> ~1564 blocks for TLP.
// LN: a row's 128 cols live in the 16 lanes sharing ty -> shfl_xor(1,2,4,8) reduce.
// DO_PROJ: also emits proj[r][0..7] = hn[r] @ [Wa_in_n|Wa_out_n|Wa_in_r|Wa_out_r]
// from the post-LN registers (feeds next iteration's action nets).
// In-place safe (out==A): each block only reads/writes its own 32-row range.
template <int HAS_B, int SKIP, int DO_LN, int DO_PROJ>
__global__ void k_gemm(const float* __restrict__ A, const float* __restrict__ W1,
                       const float* __restrict__ B, const float* __restrict__ W2,
                       const float* __restrict__ bias,
                       const float* __restrict__ ln_g, const float* __restrict__ ln_b,
                       const float* __restrict__ Wain, const float* __restrict__ Waon,
                       const float* __restrict__ Wair, const float* __restrict__ Waor,
                       float* __restrict__ out, float* __restrict__ proj, int n) {
    __shared__ float sW[32][128];
    __shared__ float sA[32][36];
    int tid = threadIdx.x;
    int rowBase = blockIdx.x * 32;
    int ty = tid >> 4, tx = tid & 15;
    int c0 = tx * 4, c1 = 64 + tx * 4;
    float acc[2][8];
#pragma unroll
    for (int i = 0; i < 2; i++)
#pragma unroll
        for (int j = 0; j < 8; j++) acc[i][j] = 0.f;

    for (int p = 0; p < 1 + HAS_B; p++) {
        const float* Ap = p ? B : A;
        const float* Wp = p ? W2 : W1;
        for (int kc = 0; kc < DIM; kc += 32) {
            __syncthreads();
            {   // stage W chunk: 32x128
                const float4* src = (const float4*)(Wp + kc * DIM);
                float4* dst = (float4*)(&sW[0][0]);
#pragma unroll
                for (int i = 0; i < 4; i++) dst[tid + i * 256] = src[tid + i * 256];
            }
            {   // stage A tile: 32 rows x 32 cols, one float4 per thread
                int r = tid >> 3, c4 = (tid & 7) * 4;
                float4 va = (rowBase + r < n)
                    ? *(const float4*)(Ap + (size_t)(rowBase + r) * DIM + kc + c4)
                    : make_float4(0.f, 0.f, 0.f, 0.f);
                *(float4*)&sA[r][c4] = va;
            }
            __syncthreads();
#pragma unroll
            for (int kk = 0; kk < 32; kk += 4) {
                float4 a0 = *(const float4*)&sA[ty][kk];
                float4 a1 = *(const float4*)&sA[ty + 16][kk];
                float a0v[4] = {a0.x, a0.y, a0.z, a0.w};
                float a1v[4] = {a1.x, a1.y, a1.z, a1.w};
#pragma unroll
                for (int q = 0; q < 4; q++) {
                    float4 w0 = *(const float4*)&sW[kk + q][c0];
                    float4 w1 = *(const float4*)&sW[kk + q][c1];
                    float wv[8] = {w0.x, w0.y, w0.z, w0.w, w1.x, w1.y, w1.z, w1.w};
#pragma unroll
                    for (int j = 0; j < 8; j++) {
                        acc[0][j] += a0v[q] * wv[j];
                        acc[1][j] += a1v[q] * wv[j];
                    }
                }
            }
        }
    }

    float4 bias0 = *(const float4*)&bias[c0];
    float4 bias1 = *(const float4*)&bias[c1];
    float bv[8] = {bias0.x, bias0.y, bias0.z, bias0.w, bias1.x, bias1.y, bias1.z, bias1.w};
    float gv[8], bbv[8];
    if (DO_LN) {
        float4 g0 = *(const float4*)&ln_g[c0];
        float4 g1 = *(const float4*)&ln_g[c1];
        float4 lb0 = *(const float4*)&ln_b[c0];
        float4 lb1 = *(const float4*)&ln_b[c1];
        gv[0]=g0.x; gv[1]=g0.y; gv[2]=g0.z; gv[3]=g0.w; gv[4]=g1.x; gv[5]=g1.y; gv[6]=g1.z; gv[7]=g1.w;
        bbv[0]=lb0.x; bbv[1]=lb0.y; bbv[2]=lb0.z; bbv[3]=lb0.w; bbv[4]=lb1.x; bbv[5]=lb1.y; bbv[6]=lb1.z; bbv[7]=lb1.w;
    }

#pragma unroll
    for (int i = 0; i < 2; i++) {
        int r = rowBase + ty + i * 16;
        if (r >= n) continue;   // uniform across the 16 lanes sharing ty
        float v[8];
        if (SKIP) {
            float4 s0 = *(const float4*)(A + (size_t)r * DIM + c0);
            float4 s1 = *(const float4*)(A + (size_t)r * DIM + c1);
            float sv[8] = {s0.x, s0.y, s0.z, s0.w, s1.x, s1.y, s1.z, s1.w};
#pragma unroll
            for (int j = 0; j < 8; j++) v[j] = fmaxf(acc[i][j] + bv[j], 0.f) + sv[j];
        } else {
#pragma unroll
            for (int j = 0; j < 8; j++) v[j] = fmaxf(acc[i][j] + bv[j], 0.f);
        }
        if (DO_LN) {
            float s = 0.f, q = 0.f;
#pragma unroll
            for (int j = 0; j < 8; j++) { s += v[j]; q += v[j] * v[j]; }
#pragma unroll
            for (int o = 1; o < 16; o <<= 1) { s += __shfl_xor(s, o); q += __shfl_xor(q, o); }
            float m = s * (1.f / DIM);
            float var = q * (1.f / DIM) - m * m;
            float inv = rsqrtf(var + 1e-5f);
#pragma unroll
            for (int j = 0; j < 8; j++) v[j] = (v[j] - m) * inv * gv[j] + bbv[j];
        }
        *(float4*)(out + (size_t)r * DIM + c0) = make_float4(v[0], v[1], v[2], v[3]);
        *(float4*)(out + (size_t)r * DIM + c1) = make_float4(v[4], v[5], v[6], v[7]);

        if (DO_PROJ) {
            // p = v . Wm[cols of this thread] for 4 weight mats (128x2 row-major)
            float pv[8];
            auto dotw = [&](const float* Wm, float& p0, float& p1) {
                float4 q0 = *(const float4*)(Wm + c0 * 2);
                float4 q1 = *(const float4*)(Wm + c0 * 2 + 4);
                float4 q2 = *(const float4*)(Wm + c1 * 2);
                float4 q3 = *(const float4*)(Wm + c1 * 2 + 4);
                p0 = v[0]*q0.x + v[1]*q0.z + v[2]*q1.x + v[3]*q1.z
                   + v[4]*q2.x + v[5]*q2.z + v[6]*q3.x + v[7]*q3.z;
                p1 = v[0]*q0.y + v[1]*q0.w + v[2]*q1.y + v[3]*q1.w
                   + v[4]*q2.y + v[5]*q2.w + v[6]*q3.y + v[7]*q3.w;
            };
            dotw(Wain, pv[0], pv[1]);
            dotw(Waon, pv[2], pv[3]);
            dotw(Wair, pv[4], pv[5]);
            dotw(Waor, pv[6], pv[7]);
#pragma unroll
            for (int o = 1; o < 16; o <<= 1)
#pragma unroll
                for (int j = 0; j < 8; j++) pv[j] += __shfl_xor(pv[j], o);
            if (tx == 0) {
                *(float4*)(proj + (size_t)r * 8)     = make_float4(pv[0], pv[1], pv[2], pv[3]);
                *(float4*)(proj + (size_t)r * 8 + 4) = make_float4(pv[4], pv[5], pv[6], pv[7]);
            }
        }
    }
}

// ---------------- decoder (input already LayerNorm'd) ----------------
__global__ void k_final(const float* __restrict__ hn, const float* __restrict__ Wdec,
                        const float* __restrict__ bdec, float* __restrict__ out, int n) {
    __shared__ float sWd[NCLS * DIM];  // transposed [c][d]
    int tid = threadIdx.x;
    for (int i = tid; i < NCLS * DIM; i += 256) {
        int d = i / NCLS, c = i % NCLS;
        sWd[c * DIM + d] = Wdec[i];
    }
    __syncthreads();
    int wid = (blockIdx.x * 256 + threadIdx.x) >> 6;
    int lane = threadIdx.x & 63;
    if (wid >= n) return;
    int d0 = lane * 2;
    float2 v = ((const float2*)(hn + (size_t)wid * DIM))[lane];
    float p[NCLS];
#pragma unroll
    for (int c = 0; c < NCLS; c++) {
        float2 w = *(const float2*)(&sWd[c * DIM + d0]);
        p[c] = v.x * w.x + v.y * w.y;
    }
#pragma unroll
    for (int o = 32; o; o >>= 1)
#pragma unroll
        for (int c = 0; c < NCLS; c++) p[c] += __shfl_xor(p[c], o);
    if (lane == 0) {
#pragma unroll
        for (int c = 0; c < NCLS; c++) out[(size_t)wid * NCLS + c] = p[c] + bdec[c];
    }
}

// ---------------- launcher ----------------
extern "C" void kernel_launch(void* const* d_in, const int* in_sizes, int n_in,
                              void* d_out, int out_size, void* d_ws, size_t ws_size,
                              hipStream_t stream) {
    const float* x      = (const float*)d_in[0];
    const int*   ei     = (const int*)d_in[1];
    const float* W_enc  = (const float*)d_in[2];
    const float* b_enc  = (const float*)d_in[3];
    const float* ln_g   = (const float*)d_in[4];
    const float* ln_b   = (const float*)d_in[5];
    const float* Wr     = (const float*)d_in[6];
    const float* Wn     = (const float*)d_in[7];
    const float* bl     = (const float*)d_in[8];
    const float* Wair   = (const float*)d_in[9];
    const float* Wain   = (const float*)d_in[10];
    const float* bain   = (const float*)d_in[11];
    const float* Waor   = (const float*)d_in[12];
    const float* Waon   = (const float*)d_in[13];
    const float* baon   = (const float*)d_in[14];
    const float* W_dec  = (const float*)d_in[15];
    const float* b_dec  = (const float*)d_in[16];
    const float* gin    = (const float*)d_in[17];
    const float* gout   = (const float*)d_in[18];

    int n = in_sizes[0] / DIM;
    int E = in_sizes[1] / 2;
    const int L = 3;

    char* wsp = (char*)d_ws;
    auto alloc = [&](size_t bytes) { char* p = wsp; wsp += (bytes + 255) / 256 * 256; return p; };
    float* hn   = (float*)alloc((size_t)n * DIM * 4);
    float* aggw = (float*)alloc((size_t)n * DIM * 4);
    float* proj = (float*)alloc((size_t)n * 8 * 4);
    int* deg       = (int*)alloc((size_t)n * 4);
    int* row_start = (int*)alloc((size_t)(n + 1) * 4);
    int* cursor    = (int*)alloc((size_t)n * 4);
    int* csr       = (int*)alloc((size_t)E * 4);
    int* in_bit    = (int*)alloc((size_t)n * 4);
    int* out_bit   = (int*)alloc((size_t)n * 4);
    int* bsum      = (int*)alloc((size_t)256 * 4);
    int* is_bl     = (int*)alloc((size_t)2 * n * 4);
    int* is_b = is_bl;
    int* is_l = is_bl + n;

    float* out_res    = (float*)d_out;                 // [n,10]
    float* out_states = out_res + (size_t)n * NCLS;    // [L,n] as float

    int ebl = (E + 255) / 256;
    int nbl = (n + 255) / 256;
    int wbl = (n + 3) / 4;        // 4 waves (nodes) per 256-thread block
    int gbl = (n + 31) / 32;      // 32-row GEMM tiles
    int nb  = (n + 1023) / 1024;  // scan blocks

    hipMemsetAsync(deg, 0, (size_t)n * 4, stream);
    k_hist<<<ebl, 256, 0, stream>>>(ei, E, deg);
    k_scan1<<<nb, 256, 0, stream>>>(deg, row_start, bsum, n);
    k_scan2<<<1, 64, 0, stream>>>(bsum, nb);
    k_scan3<<<(n + 256) / 256, 256, 0, stream>>>(row_start, cursor, bsum, n, E);
    k_fill<<<ebl, 256, 0, stream>>>(ei, E, cursor, csr);

    // encoder: hn = LN(relu(x@W_enc + b)); also emits proj for layer 0
    k_gemm<0, 0, 1, 1><<<gbl, 256, 0, stream>>>(x, W_enc, nullptr, nullptr, b_enc,
                                                ln_g, ln_b, Wain, Waon, Wair, Waor,
                                                hn, proj, n);

    for (int l = 0; l < L; l++) {
        k_action<<<nbl, 256, 0, stream>>>(proj, row_start, csr, bain, baon,
                                          gin + (size_t)l * n * 2, gout + (size_t)l * n * 2,
                                          in_bit, out_bit, is_b, is_l, n);
        k_state_edges<<<ebl, 256, 0, stream>>>(ei, E, in_bit, out_bit, is_b, is_l);
        k_aggw<<<wbl, 256, 0, stream>>>(hn, row_start, csr, in_bit, out_bit,
                                        is_b, is_l, aggw, out_states + (size_t)l * n, n);
        // hn = LN(hn + relu(hn@Wr + aggw@Wn + bl)); proj for next layer (skip on last)
        if (l + 1 < L)
            k_gemm<1, 1, 1, 1><<<gbl, 256, 0, stream>>>(hn, Wr + (size_t)l * DIM * DIM,
                                                        aggw, Wn + (size_t)l * DIM * DIM,
                                                        bl + (size_t)l * DIM,
                                                        ln_g, ln_b, Wain, Waon, Wair, Waor,
                                                        hn, proj, n);
        else
            k_gemm<1, 1, 1, 0><<<gbl, 256, 0, stream>>>(hn, Wr + (size_t)l * DIM * DIM,
                                                        aggw, Wn + (size_t)l * DIM * DIM,
                                                        bl + (size_t)l * DIM,
                                                        ln_g, ln_b, Wain, Waon, Wair, Waor,
                                                        hn, proj, n);
    }
    k_final<<<wbl, 256, 0, stream>>>(hn, W_dec, b_dec, out_res, n);
}